// Round 5
// baseline (734.968 us; speedup 1.0000x reference)
//
#include <hip/hip_runtime.h>
#include <cstddef>
#include <cstdint>

#define B_    8
#define S_    512
#define L_    15
#define D_    768
#define H_    512
#define KTOP  102
#define SL_   (S_ * L_)        // 7680
#define M_    (B_ * SL_)       // 61440

// output float offsets (concatenated return tuple)
#define OFF_SCORES 0
#define OFF_IDX    61440
#define OFF_FVECS  62256
#define OFF_FSC    688944
#define OFF_FBEG   689760
#define OFF_FEND   690576
#define OFF_SLEN   691392
#define OFF_SQ     691400
#define OFF_TRI    774632

typedef _Float16 f16;
typedef __attribute__((ext_vector_type(4))) _Float16 f16x4;
typedef __attribute__((ext_vector_type(8))) _Float16 f16x8;
typedef __attribute__((ext_vector_type(16))) float f32x16;

// persistent device scratch (rewritten fully every launch)
__device__ f16   g_W1h[512 * 768], g_W1l[512 * 768];   // W1^T split planes [n][k]
__device__ f16   g_W2h[512 * 512], g_W2l[512 * 512];   // W2^T split planes [n][k]
__device__ f16   g_h1h[(size_t)M_ * H_];               // h1 hi plane [M][512]
__device__ f16   g_h1l[(size_t)M_ * H_];               // h1 lo plane [M][512]
__device__ float g_part[8][M_];                        // layer2 partials [nb*2+wn][m]

// conflict-free swizzle: XOR byte-bits[5:4] with row-bits[2:1] (L bits [8:7]).
// For a 32-lane b128 read at rows r..r+31, quad index (4r + s') mod 8 cycles
// {0,4,1,5,2,6,3,7} per 8 rows -> zero bank conflicts.
__device__ __forceinline__ int swz(int L) { return L ^ (((L >> 7) & 3) << 4); }

__device__ __forceinline__ void gl_lds16(const void* gsrc, void* ldst) {
  __builtin_amdgcn_global_load_lds(
      (const __attribute__((address_space(1))) void*)gsrc,
      (__attribute__((address_space(3))) void*)ldst, 16, 0, 0);
}

__device__ __forceinline__ f16 hi16(float x) { return (f16)x; }
__device__ __forceinline__ f16 lo16(float x) { return (f16)(x - (float)((f16)x)); }

// ---------- prep: LDS-transpose weights into f16 hi/lo planes, coalesced ----------
__global__ void prep_kernel(const float* __restrict__ W1, const float* __restrict__ W2) {
  __shared__ float LS[64][65];
  int bid = blockIdx.x;
  const float* W; f16 *GH, *GL; int K;
  int tk, tn;
  if (bid < 96) { W = W1; GH = g_W1h; GL = g_W1l; K = 768; tk = bid >> 3; tn = bid & 7; }
  else { bid -= 96; W = W2; GH = g_W2h; GL = g_W2l; K = 512; tk = bid >> 3; tn = bid & 7; }
  const int k0 = tk * 64, n0 = tn * 64;
  const int t = threadIdx.x;
  #pragma unroll
  for (int s = 0; s < 16; ++s) {
    int r = s * 4 + (t >> 6);
    LS[r][t & 63] = W[(size_t)(k0 + r) * 512 + n0 + (t & 63)];
  }
  __syncthreads();
  #pragma unroll
  for (int s = 0; s < 16; ++s) {
    int n = s * 4 + (t >> 6);
    int k = t & 63;
    float x = LS[k][n];
    GH[(size_t)(n0 + n) * K + k0 + k] = hi16(x);
    GL[(size_t)(n0 + n) * K + k0 + k] = lo16(x);
  }
}

// ---------- split-f16 MFMA GEMM, double-buffered ----------
template <int LAYER>
__global__ __launch_bounds__(256, 2)
void gemm_kernel(const float* __restrict__ V, const float* __restrict__ bias,
                 const float* __restrict__ w3) {
  constexpr int K = (LAYER == 1) ? 768 : 512;
  constexpr int NT = K / 32;
  __shared__ __align__(16) char lds[65536];   // 2 buffers x {Ah,Al,Bh,Bl} x 8KB

  const int t = threadIdx.x;
  const int lane = t & 63;
  const int w = t >> 6;
  const int wm = w >> 1, wn = w & 1;

  const int o = (blockIdx.x & 7) * 240 + (blockIdx.x >> 3);  // XCD swizzle, 1920=8*240
  const int nb = o & 3, mb = o >> 2;
  const int m0 = mb * 128, n0 = nb * 128;

  const f16* WH = (LAYER == 1) ? g_W1h : g_W2h;
  const f16* WL = (LAYER == 1) ? g_W1l : g_W2l;

  f32x16 acc[2][2];
  #pragma unroll
  for (int i = 0; i < 2; ++i)
    #pragma unroll
    for (int j = 0; j < 2; ++j) acc[i][j] = (f32x16)0.0f;

  auto stageB = [&](int it) {
    const int k0 = it * 32;
    char* Bh = lds + (it & 1) * 32768 + 16384;
    #pragma unroll
    for (int h = 0; h < 2; ++h) {
      int P = (h * 4 + w) * 1024 + lane * 16;
      int Lg = swz(P);
      int r = Lg >> 6, q = (Lg >> 4) & 3;
      size_t go = (size_t)(n0 + r) * K + k0 + q * 8;
      gl_lds16(WH + go, Bh + P);
      gl_lds16(WL + go, Bh + 8192 + P);
    }
  };
  auto stageA2 = [&](int it) {
    const int k0 = it * 32;
    char* Ah = lds + (it & 1) * 32768;
    #pragma unroll
    for (int h = 0; h < 2; ++h) {
      int P = (h * 4 + w) * 1024 + lane * 16;
      int Lg = swz(P);
      int r = Lg >> 6, q = (Lg >> 4) & 3;
      size_t go = (size_t)(m0 + r) * 512 + k0 + q * 8;
      gl_lds16(g_h1h + go, Ah + P);
      gl_lds16(g_h1l + go, Ah + 8192 + P);
    }
  };
  auto loadA1 = [&](int it, float4* vv) {
    const int k0 = it * 32;
    const int row = t >> 1, ks = (t & 1) * 16;
    const float* src = V + (size_t)(m0 + row) * 768 + k0 + ks;
    vv[0] = *(const float4*)(src);
    vv[1] = *(const float4*)(src + 4);
    vv[2] = *(const float4*)(src + 8);
    vv[3] = *(const float4*)(src + 12);
  };
  auto writeA1 = [&](int it, const float4* vv) {
    char* Ah = lds + (it & 1) * 32768;
    const int row = t >> 1, ks = (t & 1) * 16;
    #pragma unroll
    for (int j = 0; j < 4; ++j) {
      f16x4 hv, lv;
      hv[0] = hi16(vv[j].x); lv[0] = lo16(vv[j].x);
      hv[1] = hi16(vv[j].y); lv[1] = lo16(vv[j].y);
      hv[2] = hi16(vv[j].z); lv[2] = lo16(vv[j].z);
      hv[3] = hi16(vv[j].w); lv[3] = lo16(vv[j].w);
      int P = swz(row * 64 + (ks + j * 4) * 2);
      *(f16x4*)(Ah + P) = hv;
      *(f16x4*)(Ah + 8192 + P) = lv;
    }
  };
  auto compute = [&](int it) {
    const char* base = lds + (it & 1) * 32768;
    #pragma unroll
    for (int kk = 0; kk < 2; ++kk) {
      const int intra = kk * 32 + (lane >> 5) * 16;
      f16x8 ah[2], al[2], bh[2], bl[2];
      #pragma unroll
      for (int mt = 0; mt < 2; ++mt) {
        int P = swz((wm * 64 + mt * 32 + (lane & 31)) * 64 + intra);
        ah[mt] = *(const f16x8*)(base + P);
        al[mt] = *(const f16x8*)(base + 8192 + P);
      }
      #pragma unroll
      for (int nt = 0; nt < 2; ++nt) {
        int P = swz((wn * 64 + nt * 32 + (lane & 31)) * 64 + intra);
        bh[nt] = *(const f16x8*)(base + 16384 + P);
        bl[nt] = *(const f16x8*)(base + 24576 + P);
      }
      #pragma unroll
      for (int mt = 0; mt < 2; ++mt)
        #pragma unroll
        for (int nt = 0; nt < 2; ++nt) {
          acc[mt][nt] = __builtin_amdgcn_mfma_f32_32x32x16_f16(ah[mt], bh[nt], acc[mt][nt], 0, 0, 0);
          acc[mt][nt] = __builtin_amdgcn_mfma_f32_32x32x16_f16(al[mt], bh[nt], acc[mt][nt], 0, 0, 0);
          acc[mt][nt] = __builtin_amdgcn_mfma_f32_32x32x16_f16(ah[mt], bl[nt], acc[mt][nt], 0, 0, 0);
        }
    }
  };

  // prologue
  float4 vv[4];
  if (LAYER == 1) { loadA1(0, vv); stageB(0); writeA1(0, vv); }
  else { stageB(0); stageA2(0); }
  __syncthreads();

  for (int it = 0; it < NT; ++it) {
    const bool nx = (it + 1 < NT);
    if (nx) {
      stageB(it + 1);
      if (LAYER == 1) loadA1(it + 1, vv); else stageA2(it + 1);
    }
    compute(it);
    if (nx && LAYER == 1) writeA1(it + 1, vv);
    __syncthreads();
  }

  // epilogue
  const int half = lane >> 5;
  if (LAYER == 1) {
    #pragma unroll
    for (int mt = 0; mt < 2; ++mt)
      #pragma unroll
      for (int nt = 0; nt < 2; ++nt) {
        int col = n0 + wn * 64 + nt * 32 + (lane & 31);
        float bb = bias[col];
        #pragma unroll
        for (int r = 0; r < 16; ++r) {
          int m = m0 + wm * 64 + mt * 32 + (r & 3) + ((r >> 2) << 3) + (half << 2);
          float v = fmaxf(acc[mt][nt][r] + bb, 0.0f);
          g_h1h[(size_t)m * 512 + col] = hi16(v);
          g_h1l[(size_t)m * 512 + col] = lo16(v);
        }
      }
  } else {
    #pragma unroll
    for (int mt = 0; mt < 2; ++mt) {
      float s[16];
      #pragma unroll
      for (int r = 0; r < 16; ++r) s[r] = 0.0f;
      #pragma unroll
      for (int nt = 0; nt < 2; ++nt) {
        int col = n0 + wn * 64 + nt * 32 + (lane & 31);
        float bb = bias[col];
        float wv = w3[col];
        #pragma unroll
        for (int r = 0; r < 16; ++r)
          s[r] += fmaxf(acc[mt][nt][r] + bb, 0.0f) * wv;
      }
      #pragma unroll
      for (int off = 1; off < 32; off <<= 1)
        #pragma unroll
        for (int r = 0; r < 16; ++r) s[r] += __shfl_xor(s[r], off, 64);
      if ((lane & 31) == 0) {
        #pragma unroll
        for (int r = 0; r < 16; ++r) {
          int m = m0 + wm * 64 + mt * 32 + (r & 3) + ((r >> 2) << 3) + (half << 2);
          g_part[nb * 2 + wn][m] = s[r];
        }
      }
    }
  }
}

// ---------- finalize: sum partials + bias3 + mask penalty ----------
__global__ void finalize_kernel(const float* __restrict__ mask, const float* __restrict__ B3,
                                float* __restrict__ out) {
  int i = blockIdx.x * 256 + threadIdx.x;
  float s = 0.0f;
  #pragma unroll
  for (int p = 0; p < 8; ++p) s += g_part[p][i];
  out[OFF_SCORES + i] = s + B3[0] - (1.0f - mask[i]) * 10000.0f;
}

// ---------- top-k / gather / masks (validated) ----------
__global__ void topk_kernel(const float* __restrict__ scores,
                            const int* __restrict__ seqlen,
                            float* __restrict__ out,
                            int* __restrict__ ws_idx,
                            int* __restrict__ ws_sl) {
  __shared__ float vals[SL_];
  __shared__ float rv[4];
  __shared__ int ri[4];
  __shared__ int sel[KTOP];

  const int t = threadIdx.x;
  const int b = blockIdx.x;
  const float* s = scores + (size_t)b * SL_;

  for (int i = t; i < SL_; i += 256) vals[i] = s[i];
  __syncthreads();

  for (int it = 0; it < KTOP; ++it) {
    float bv = -3.0e38f;
    int bi = 0x7fffffff;
    for (int i = t; i < SL_; i += 256) {
      float v = vals[i];
      if (v > bv) { bv = v; bi = i; }
    }
    #pragma unroll
    for (int off = 32; off > 0; off >>= 1) {
      float ov = __shfl_down(bv, off, 64);
      int oi = __shfl_down(bi, off, 64);
      if (ov > bv || (ov == bv && oi < bi)) { bv = ov; bi = oi; }
    }
    if ((t & 63) == 0) { rv[t >> 6] = bv; ri[t >> 6] = bi; }
    __syncthreads();
    if (t == 0) {
      float fb = rv[0]; int fi = ri[0];
      #pragma unroll
      for (int wv = 1; wv < 4; ++wv)
        if (rv[wv] > fb || (rv[wv] == fb && ri[wv] < fi)) { fb = rv[wv]; fi = ri[wv]; }
      sel[it] = fi;
      vals[fi] = -3.0e38f;
    }
    __syncthreads();
  }

  for (int pass = 0; pass < KTOP; ++pass) {
    int i = 2 * t + (pass & 1);
    if (i + 1 < KTOP) {
      int a = sel[i], c = sel[i + 1];
      if (a > c) { sel[i] = c; sel[i + 1] = a; }
    }
    __syncthreads();
  }

  if (t < KTOP) {
    out[OFF_IDX + b * KTOP + t] = (float)sel[t];
    ws_idx[b * KTOP + t] = sel[t];
  }
  if (t == 0) {
    int len = seqlen[b];
    int v = (int)(0.2f * (float)len);
    if (v > KTOP) v = KTOP;
    out[OFF_SLEN + b] = (float)v;
    ws_sl[b] = v;
  }
}

__global__ void gather_kernel(const float* __restrict__ V,
                              const int* __restrict__ sbeg,
                              const int* __restrict__ send,
                              float* __restrict__ out,
                              const int* __restrict__ ws_idx) {
  const int blk = blockIdx.x;
  const int b = blk / KTOP;
  const int t = threadIdx.x;
  const int sid = ws_idx[blk];
  const float4* s4 = reinterpret_cast<const float4*>(V + ((size_t)b * SL_ + sid) * D_);
  float4* d4 = reinterpret_cast<float4*>(out + OFF_FVECS + (size_t)blk * D_);
  d4[t] = s4[t];
  if (t == 0) {
    int gi = b * SL_ + sid;
    out[OFF_FSC + blk] = out[OFF_SCORES + gi];
    out[OFF_FBEG + blk] = (float)sbeg[gi];
    out[OFF_FEND + blk] = (float)send[gi];
  }
}

__global__ void masks_kernel(float* __restrict__ out, const int* __restrict__ ws_sl) {
  int e = blockIdx.x * 256 + threadIdx.x;
  if (e >= B_ * KTOP * KTOP) return;
  int b = e / (KTOP * KTOP);
  int r = e - b * (KTOP * KTOP);
  int i = r / KTOP;
  int j = r - i * KTOP;
  int len = ws_sl[b];
  float sq = (i < len && j < len) ? 1.0f : 0.0f;
  out[OFF_SQ + e] = sq;
  out[OFF_TRI + e] = (j <= i) ? sq : 0.0f;
}

extern "C" void kernel_launch(void* const* d_in, const int* in_sizes, int n_in,
                              void* d_out, int out_size, void* d_ws, size_t ws_size,
                              hipStream_t stream) {
  const float* V    = (const float*)d_in[0];
  const float* mask = (const float*)d_in[1];
  const int*   sbeg = (const int*)d_in[2];
  const int*   send = (const int*)d_in[3];
  const int*   slen = (const int*)d_in[4];
  const float* W1 = (const float*)d_in[5];
  const float* B1 = (const float*)d_in[6];
  const float* W2 = (const float*)d_in[7];
  const float* B2 = (const float*)d_in[8];
  const float* W3 = (const float*)d_in[9];
  const float* B3 = (const float*)d_in[10];
  float* out = (float*)d_out;
  int* ws_idx = (int*)d_ws;
  int* ws_sl = ws_idx + B_ * KTOP;

  prep_kernel<<<160, 256, 0, stream>>>(W1, W2);
  gemm_kernel<1><<<1920, 256, 0, stream>>>(V, B1, nullptr);
  gemm_kernel<2><<<1920, 256, 0, stream>>>(nullptr, B2, W3);
  finalize_kernel<<<240, 256, 0, stream>>>(mask, B3, out);
  topk_kernel<<<B_, 256, 0, stream>>>(out, slen, out, ws_idx, ws_sl);
  gather_kernel<<<B_ * KTOP, 192, 0, stream>>>(V, sbeg, send, out, ws_idx);
  masks_kernel<<<(B_ * KTOP * KTOP + 255) / 256, 256, 0, stream>>>(out, ws_sl);
}

// Round 6
// 584.611 us; speedup vs baseline: 1.2572x; 1.2572x over previous
//
#include <hip/hip_runtime.h>
#include <cstddef>
#include <cstdint>

#define B_    8
#define S_    512
#define L_    15
#define D_    768
#define H_    512
#define KTOP  102
#define SL_   (S_ * L_)        // 7680
#define M_    (B_ * SL_)       // 61440

// output float offsets (concatenated return tuple)
#define OFF_SCORES 0
#define OFF_IDX    61440
#define OFF_FVECS  62256
#define OFF_FSC    688944
#define OFF_FBEG   689760
#define OFF_FEND   690576
#define OFF_SLEN   691392
#define OFF_SQ     691400
#define OFF_TRI    774632

typedef _Float16 f16;
typedef __attribute__((ext_vector_type(4))) _Float16 f16x4;
typedef __attribute__((ext_vector_type(8))) _Float16 f16x8;
typedef __attribute__((ext_vector_type(16))) float f32x16;

// persistent device scratch (rewritten fully every launch)
__device__ f16   g_W1h[512 * 768], g_W1l[512 * 768];   // W1^T split planes [n][k]
__device__ f16   g_W2h[512 * 512], g_W2l[512 * 512];   // W2^T split planes [n][k]
__device__ f16   g_h1h[(size_t)M_ * H_];               // h1 hi plane [M][512]
__device__ f16   g_h1l[(size_t)M_ * H_];               // h1 lo plane [M][512]
__device__ float g_part[8][M_];                        // layer2 partials [nb*2+wn][m]

// conflict-free read swizzle: XOR byte-bits[5:4] with row-bits[2:1] (L bits 8:7).
// An 8-lane b128 group covers rows r..r+7: (parity, quad^rowbits) hits all 8
// distinct 4-bank groups -> 0-way conflict on ds_read_b128.
__device__ __forceinline__ int swz(int L) { return L ^ (((L >> 7) & 3) << 4); }

__device__ __forceinline__ void gl_lds16(const void* gsrc, void* ldst) {
  __builtin_amdgcn_global_load_lds(
      (const __attribute__((address_space(1))) void*)gsrc,
      (__attribute__((address_space(3))) void*)ldst, 16, 0, 0);
}

__device__ __forceinline__ f16 hi16(float x) { return (f16)x; }
__device__ __forceinline__ f16 lo16(float x) { return (f16)(x - (float)((f16)x)); }

// ---------- prep: LDS-transpose weights into f16 hi/lo planes, coalesced ----------
__global__ void prep_kernel(const float* __restrict__ W1, const float* __restrict__ W2) {
  __shared__ float LS[64][65];
  int bid = blockIdx.x;
  const float* W; f16 *GH, *GL; int K;
  int tk, tn;
  if (bid < 96) { W = W1; GH = g_W1h; GL = g_W1l; K = 768; tk = bid >> 3; tn = bid & 7; }
  else { bid -= 96; W = W2; GH = g_W2h; GL = g_W2l; K = 512; tk = bid >> 3; tn = bid & 7; }
  const int k0 = tk * 64, n0 = tn * 64;
  const int t = threadIdx.x;
  #pragma unroll
  for (int s = 0; s < 16; ++s) {
    int r = s * 4 + (t >> 6);
    LS[r][t & 63] = W[(size_t)(k0 + r) * 512 + n0 + (t & 63)];
  }
  __syncthreads();
  #pragma unroll
  for (int s = 0; s < 16; ++s) {
    int n = s * 4 + (t >> 6);
    int k = t & 63;
    float x = LS[k][n];
    GH[(size_t)(n0 + n) * K + k0 + k] = hi16(x);
    GL[(size_t)(n0 + n) * K + k0 + k] = lo16(x);
  }
}

// ---------- split-f16 MFMA GEMM, single 32KB buffer (4 blocks/CU) ----------
template <int LAYER>
__global__ __launch_bounds__(256, 4)
void gemm_kernel(const float* __restrict__ V, const float* __restrict__ bias,
                 const float* __restrict__ w3) {
  constexpr int K = (LAYER == 1) ? 768 : 512;
  constexpr int NT = K / 32;
  __shared__ __align__(16) char lds[32768];   // {Ah,Al,Bh,Bl} x 8KB

  const int t = threadIdx.x;
  const int lane = t & 63;
  const int w = t >> 6;
  const int wm = w >> 1, wn = w & 1;

  const int o = (blockIdx.x & 7) * 240 + (blockIdx.x >> 3);  // XCD swizzle, 1920=8*240
  const int nb = o & 3, mb = o >> 2;
  const int m0 = mb * 128, n0 = nb * 128;

  const f16* WH = (LAYER == 1) ? g_W1h : g_W2h;
  const f16* WL = (LAYER == 1) ? g_W1l : g_W2l;

  f32x16 acc[2][2];
  #pragma unroll
  for (int i = 0; i < 2; ++i)
    #pragma unroll
    for (int j = 0; j < 2; ++j) acc[i][j] = (f32x16)0.0f;

  for (int it = 0; it < NT; ++it) {
    const int k0 = it * 32;
    // ---- stage B (async DMA first, overlaps with A split work)
    #pragma unroll
    for (int h = 0; h < 2; ++h) {
      int P = (h * 4 + w) * 1024 + lane * 16;
      int Lg = swz(P);
      int r = Lg >> 6, q = (Lg >> 4) & 3;
      size_t go = (size_t)(n0 + r) * K + k0 + q * 8;
      gl_lds16(WH + go, lds + 16384 + P);
      gl_lds16(WL + go, lds + 24576 + P);
    }
    // ---- stage A
    if (LAYER == 1) {
      const int row = t >> 1, ks = (t & 1) * 16;
      const float* src = V + (size_t)(m0 + row) * 768 + k0 + ks;
      float4 vv[4];
      vv[0] = *(const float4*)(src);
      vv[1] = *(const float4*)(src + 4);
      vv[2] = *(const float4*)(src + 8);
      vv[3] = *(const float4*)(src + 12);
      #pragma unroll
      for (int j = 0; j < 4; ++j) {
        f16x4 hv, lv;
        hv[0] = hi16(vv[j].x); lv[0] = lo16(vv[j].x);
        hv[1] = hi16(vv[j].y); lv[1] = lo16(vv[j].y);
        hv[2] = hi16(vv[j].z); lv[2] = lo16(vv[j].z);
        hv[3] = hi16(vv[j].w); lv[3] = lo16(vv[j].w);
        int P = swz(row * 64 + (ks + j * 4) * 2);
        *(f16x4*)(lds + P) = hv;
        *(f16x4*)(lds + 8192 + P) = lv;
      }
    } else {
      #pragma unroll
      for (int h = 0; h < 2; ++h) {
        int P = (h * 4 + w) * 1024 + lane * 16;
        int Lg = swz(P);
        int r = Lg >> 6, q = (Lg >> 4) & 3;
        size_t go = (size_t)(m0 + r) * 512 + k0 + q * 8;
        gl_lds16(g_h1h + go, lds + P);
        gl_lds16(g_h1l + go, lds + 8192 + P);
      }
    }
    __syncthreads();
    // ---- compute: 2 ksteps of 32x32x16, 3 split-products each
    #pragma unroll
    for (int kk = 0; kk < 2; ++kk) {
      const int intra = kk * 32 + (lane >> 5) * 16;
      f16x8 ah[2], al[2], bh[2], bl[2];
      #pragma unroll
      for (int mt = 0; mt < 2; ++mt) {
        int P = swz((wm * 64 + mt * 32 + (lane & 31)) * 64 + intra);
        ah[mt] = *(const f16x8*)(lds + P);
        al[mt] = *(const f16x8*)(lds + 8192 + P);
      }
      #pragma unroll
      for (int nt = 0; nt < 2; ++nt) {
        int P = swz((wn * 64 + nt * 32 + (lane & 31)) * 64 + intra);
        bh[nt] = *(const f16x8*)(lds + 16384 + P);
        bl[nt] = *(const f16x8*)(lds + 24576 + P);
      }
      #pragma unroll
      for (int mt = 0; mt < 2; ++mt)
        #pragma unroll
        for (int nt = 0; nt < 2; ++nt) {
          acc[mt][nt] = __builtin_amdgcn_mfma_f32_32x32x16_f16(ah[mt], bh[nt], acc[mt][nt], 0, 0, 0);
          acc[mt][nt] = __builtin_amdgcn_mfma_f32_32x32x16_f16(al[mt], bh[nt], acc[mt][nt], 0, 0, 0);
          acc[mt][nt] = __builtin_amdgcn_mfma_f32_32x32x16_f16(ah[mt], bl[nt], acc[mt][nt], 0, 0, 0);
        }
    }
    __syncthreads();
  }

  // epilogue
  const int half = lane >> 5;
  if (LAYER == 1) {
    #pragma unroll
    for (int mt = 0; mt < 2; ++mt)
      #pragma unroll
      for (int nt = 0; nt < 2; ++nt) {
        int col = n0 + wn * 64 + nt * 32 + (lane & 31);
        float bb = bias[col];
        #pragma unroll
        for (int r = 0; r < 16; ++r) {
          int m = m0 + wm * 64 + mt * 32 + (r & 3) + ((r >> 2) << 3) + (half << 2);
          float v = fmaxf(acc[mt][nt][r] + bb, 0.0f);
          g_h1h[(size_t)m * 512 + col] = hi16(v);
          g_h1l[(size_t)m * 512 + col] = lo16(v);
        }
      }
  } else {
    #pragma unroll
    for (int mt = 0; mt < 2; ++mt) {
      float s[16];
      #pragma unroll
      for (int r = 0; r < 16; ++r) s[r] = 0.0f;
      #pragma unroll
      for (int nt = 0; nt < 2; ++nt) {
        int col = n0 + wn * 64 + nt * 32 + (lane & 31);
        float bb = bias[col];
        float wv = w3[col];
        #pragma unroll
        for (int r = 0; r < 16; ++r)
          s[r] += fmaxf(acc[mt][nt][r] + bb, 0.0f) * wv;
      }
      #pragma unroll
      for (int off = 1; off < 32; off <<= 1)
        #pragma unroll
        for (int r = 0; r < 16; ++r) s[r] += __shfl_xor(s[r], off, 64);
      if ((lane & 31) == 0) {
        #pragma unroll
        for (int r = 0; r < 16; ++r) {
          int m = m0 + wm * 64 + mt * 32 + (r & 3) + ((r >> 2) << 3) + (half << 2);
          g_part[nb * 2 + wn][m] = s[r];
        }
      }
    }
  }
}

// ---------- finalize: sum partials + bias3 + mask penalty ----------
__global__ void finalize_kernel(const float* __restrict__ mask, const float* __restrict__ B3,
                                float* __restrict__ out) {
  int i = blockIdx.x * 256 + threadIdx.x;
  float s = 0.0f;
  #pragma unroll
  for (int p = 0; p < 8; ++p) s += g_part[p][i];
  out[OFF_SCORES + i] = s + B3[0] - (1.0f - mask[i]) * 10000.0f;
}

// ---------- top-k via binary radix-select (exact, lax.top_k tie semantics) ----------
__global__ void topk_kernel(const float* __restrict__ scores,
                            const int* __restrict__ seqlen,
                            float* __restrict__ out,
                            int* __restrict__ ws_idx,
                            int* __restrict__ ws_sl) {
  __shared__ uint32_t uk[SL_];       // order-preserving transformed keys
  __shared__ int red[4];
  __shared__ int sel[KTOP];
  __shared__ int eq[128];
  __shared__ int cg, ce;

  const int t = threadIdx.x;   // 256
  const int b = blockIdx.x;
  const float* s = scores + (size_t)b * SL_;

  for (int i = t; i < SL_; i += 256) {
    uint32_t u = __float_as_uint(s[i]);
    uk[i] = (u & 0x80000000u) ? ~u : (u | 0x80000000u);  // key order == float order
  }
  if (t == 0) { cg = 0; ce = 0; }
  __syncthreads();

  // find T = KTOP-th largest key, k = how many ties at T to take
  uint32_t pfx = 0;
  int k = KTOP;
  for (int p = 31; p >= 0; --p) {
    uint32_t bit = 1u << p;
    uint32_t dmb = ~(bit - 1u);          // bits 31..p
    uint32_t target = pfx | bit;
    int cnt = 0;
    for (int i = t; i < SL_; i += 256)
      cnt += ((uk[i] & dmb) == target);
    #pragma unroll
    for (int off = 32; off > 0; off >>= 1) cnt += __shfl_down(cnt, off, 64);
    if ((t & 63) == 0) red[t >> 6] = cnt;
    __syncthreads();
    int tot = red[0] + red[1] + red[2] + red[3];
    if (tot >= k) pfx = target; else k -= tot;
    __syncthreads();
  }
  const uint32_t T = pfx;

  // collect: all keys > T, plus lowest-index keys == T (k of them)
  for (int i = t; i < SL_; i += 256) {
    uint32_t key = uk[i];
    if (key > T) {
      int pos = atomicAdd(&cg, 1);
      sel[pos] = i;
    } else if (key == T) {
      int pos = atomicAdd(&ce, 1);
      if (pos < 128) eq[pos] = i;
    }
  }
  __syncthreads();
  if (t == 0) {
    int ne = ce < 128 ? ce : 128;
    // insertion sort eq ascending (ne is tiny in practice)
    for (int i = 1; i < ne; ++i) {
      int v = eq[i], j = i - 1;
      while (j >= 0 && eq[j] > v) { eq[j + 1] = eq[j]; --j; }
      eq[j + 1] = v;
    }
    for (int j = 0; j < k; ++j) sel[cg + j] = eq[j];
  }
  __syncthreads();

  // odd-even transposition sort ascending (102 elements)
  for (int pass = 0; pass < KTOP; ++pass) {
    int i = 2 * t + (pass & 1);
    if (i + 1 < KTOP) {
      int a = sel[i], c = sel[i + 1];
      if (a > c) { sel[i] = c; sel[i + 1] = a; }
    }
    __syncthreads();
  }

  if (t < KTOP) {
    out[OFF_IDX + b * KTOP + t] = (float)sel[t];
    ws_idx[b * KTOP + t] = sel[t];
  }
  if (t == 0) {
    int len = seqlen[b];
    int v = (int)(0.2f * (float)len);
    if (v > KTOP) v = KTOP;
    out[OFF_SLEN + b] = (float)v;
    ws_sl[b] = v;
  }
}

__global__ void gather_kernel(const float* __restrict__ V,
                              const int* __restrict__ sbeg,
                              const int* __restrict__ send,
                              float* __restrict__ out,
                              const int* __restrict__ ws_idx) {
  const int blk = blockIdx.x;
  const int b = blk / KTOP;
  const int t = threadIdx.x;
  const int sid = ws_idx[blk];
  const float4* s4 = reinterpret_cast<const float4*>(V + ((size_t)b * SL_ + sid) * D_);
  float4* d4 = reinterpret_cast<float4*>(out + OFF_FVECS + (size_t)blk * D_);
  d4[t] = s4[t];
  if (t == 0) {
    int gi = b * SL_ + sid;
    out[OFF_FSC + blk] = out[OFF_SCORES + gi];
    out[OFF_FBEG + blk] = (float)sbeg[gi];
    out[OFF_FEND + blk] = (float)send[gi];
  }
}

__global__ void masks_kernel(float* __restrict__ out, const int* __restrict__ ws_sl) {
  int e = blockIdx.x * 256 + threadIdx.x;
  if (e >= B_ * KTOP * KTOP) return;
  int b = e / (KTOP * KTOP);
  int r = e - b * (KTOP * KTOP);
  int i = r / KTOP;
  int j = r - i * KTOP;
  int len = ws_sl[b];
  float sq = (i < len && j < len) ? 1.0f : 0.0f;
  out[OFF_SQ + e] = sq;
  out[OFF_TRI + e] = (j <= i) ? sq : 0.0f;
}

extern "C" void kernel_launch(void* const* d_in, const int* in_sizes, int n_in,
                              void* d_out, int out_size, void* d_ws, size_t ws_size,
                              hipStream_t stream) {
  const float* V    = (const float*)d_in[0];
  const float* mask = (const float*)d_in[1];
  const int*   sbeg = (const int*)d_in[2];
  const int*   send = (const int*)d_in[3];
  const int*   slen = (const int*)d_in[4];
  const float* W1 = (const float*)d_in[5];
  const float* B1 = (const float*)d_in[6];
  const float* W2 = (const float*)d_in[7];
  const float* B2 = (const float*)d_in[8];
  const float* W3 = (const float*)d_in[9];
  const float* B3 = (const float*)d_in[10];
  float* out = (float*)d_out;
  int* ws_idx = (int*)d_ws;
  int* ws_sl = ws_idx + B_ * KTOP;

  prep_kernel<<<160, 256, 0, stream>>>(W1, W2);
  gemm_kernel<1><<<1920, 256, 0, stream>>>(V, B1, nullptr);
  gemm_kernel<2><<<1920, 256, 0, stream>>>(nullptr, B2, W3);
  finalize_kernel<<<240, 256, 0, stream>>>(mask, B3, out);
  topk_kernel<<<B_, 256, 0, stream>>>(out, slen, out, ws_idx, ws_sl);
  gather_kernel<<<B_ * KTOP, 192, 0, stream>>>(V, sbeg, send, out, ws_idx);
  masks_kernel<<<(B_ * KTOP * KTOP + 255) / 256, 256, 0, stream>>>(out, ws_sl);
}